// Round 15
// baseline (52.400 us; speedup 1.0000x reference)
//
#include <hip/hip_runtime.h>
#include <math.h>

#define NB_TOTAL 65536
#define OUTS 773            // 2 + 514 + 257

typedef float f32x4 __attribute__((ext_vector_type(4)));
typedef float f32x2 __attribute__((ext_vector_type(2)));

// Output row layout (f32):
//  [0..1] x31 | [2+i] G flat i=2j+comp (512 vals) | [514,515] G_o
//  [516+m] h_s | [772] h_o
//
// prm row layout (16 f32):
//  [0]A0 [1]tvs [2]tvc [3]A1 | [4]tc [5]ts [6]x31_0 [7]x31_1
//  [8]Go0 [9]Go1 [10]ho [11]- | [12]C [13]u [14]w [15]pp
//  G0(j) = A0 - tvs*ox + tvc*oy ; G1(j) = A1 + tc*ox + ts*oy
//  h(m)  = C + u*ox + w*oy + pp*q ; q = ox^2+oy^2-R^2
//
// R15: LINEAR-ROW-PER-WAVE phase B. Wave wv writes rows [wv*16, wv*16+16)
// of its block — a linear ~49.5KB store stream per wave (vs stride-4 rows
// = 12.4KB jumps in R10/R14). Tests the HBM-page/stream-locality theory of
// B's 5.1 vs 6.7 TB/s gap. Row phases cycle 0..3 -> all 4 templates per
// wave; R9's spill avoided by (a) sched_barrier(0) between rows (one row
// in flight), (b) H-path feats in LDS via per-phase SHIFTED copies so every
// ds_read_b128 stays 16B-aligned (R13: per-row LDS reads are latency-null).
// R7 lesson: only 16B-ALIGNED dwordx4 global stores.

__device__ __forceinline__ int iclamp(int v, int lo, int hi) {
    return v < lo ? lo : (v > hi ? hi : v);
}

struct GFeats {
    float ax[4], ay[4];     // obstacles 2l-1 .. 2l+2   (G chunk A window)
    float bx[4], by[4];     // obstacles 2l+127 .. 2l+130 (G chunk B window)
    float o0x, o0y;         // obstacle 0 (head G eval, PH 0/1)
    float e255x, e255y;     // obstacle 255 (G511, PH3)
    float Tx[3], Ty[3], Tq[3]; // h[253..255] feats (tail, lane 1)
};

// One output row, direct aligned stores. Algebra lifted verbatim from the
// correctness-proven R9/R14 kernels; H-feats come from shifted LDS copies.
template<int PH>
__device__ __forceinline__ void b_row2(
    int row, int rloc, int l,
    const float (&prm)[64][16],
    const float (&oxy4)[4][260][2],
    const float (&Q)[4][260],
    const GFeats& f,
    float* __restrict__ out)
{
    const f32x4 c0 = *(const f32x4*)&prm[rloc][0];
    const f32x4 c1 = *(const f32x4*)&prm[rloc][4];
    const f32x4 c2 = *(const f32x4*)&prm[rloc][8];
    const f32x4 c3 = *(const f32x4*)&prm[rloc][12];
    const float A0 = c0.x, tvs = c0.y, tvc = c0.z, A1 = c0.w;
    const float tc = c1.x, ts  = c1.y, x31_0 = c1.z, x31_1 = c1.w;
    const float Go0 = c2.x, Go1 = c2.y, ho = c2.z;
    const float C = c3.x, u = c3.y, w = c3.z, pp = c3.w;

    auto G0 = [&](float X, float Y) { return fmaf(Y, tvc, fmaf(-X, tvs, A0)); };
    auto G1 = [&](float X, float Y) { return fmaf(Y, ts,  fmaf( X, tc,  A1)); };
    auto H  = [&](float X, float Y, float Qv) {
        return fmaf(pp, Qv, fmaf(w, Y, fmaf(u, X, C)));
    };

    // H-window feats: m = 4l-PH+t ; shifted copies keep b128 16B-aligned.
    const f32x4 qw  = *(const f32x4*)&Q[PH][4 * l];           // q[m0..m3]
    const f32x4 xy0 = *(const f32x4*)&oxy4[PH][4 * l][0];     // (x,y) m0,m1
    const f32x4 xy1 = *(const f32x4*)&oxy4[PH][4 * l + 2][0]; // (x,y) m2,m3

    const unsigned base = (unsigned)row * 773u;
    float* a0p = out + (base - (unsigned)PH);        // 16B-aligned

    // chunk A: k = l+1  (R9-verbatim mapping on union window ax=2l-1..2l+2)
    f32x4 vA;
    if (PH == 0) vA = (f32x4){G0(f.ax[2],f.ay[2]), G1(f.ax[2],f.ay[2]),
                              G0(f.ax[3],f.ay[3]), G1(f.ax[3],f.ay[3])};
    if (PH == 1) vA = (f32x4){G1(f.ax[1],f.ay[1]), G0(f.ax[2],f.ay[2]),
                              G1(f.ax[2],f.ay[2]), G0(f.ax[3],f.ay[3])};
    if (PH == 2) vA = (f32x4){G0(f.ax[1],f.ay[1]), G1(f.ax[1],f.ay[1]),
                              G0(f.ax[2],f.ay[2]), G1(f.ax[2],f.ay[2])};
    if (PH == 3) vA = (f32x4){G1(f.ax[0],f.ay[0]), G0(f.ax[1],f.ay[1]),
                              G1(f.ax[1],f.ay[1]), G0(f.ax[2],f.ay[2])};
    if (PH == 3 && l == 0) vA.x = x31_1;             // f=1
    *(f32x4*)(a0p + 4 * (l + 1)) = vA;

    // chunk B: k = l+65
    f32x4 vB;
    if (PH == 0) vB = (f32x4){G0(f.bx[2],f.by[2]), G1(f.bx[2],f.by[2]),
                              G0(f.bx[3],f.by[3]), G1(f.bx[3],f.by[3])};
    if (PH == 1) vB = (f32x4){G1(f.bx[1],f.by[1]), G0(f.bx[2],f.by[2]),
                              G1(f.bx[2],f.by[2]), G0(f.bx[3],f.by[3])};
    if (PH == 2) vB = (f32x4){G0(f.bx[1],f.by[1]), G1(f.bx[1],f.by[1]),
                              G0(f.bx[2],f.by[2]), G1(f.bx[2],f.by[2])};
    if (PH == 3) vB = (f32x4){G1(f.bx[0],f.by[0]), G0(f.bx[1],f.by[1]),
                              G1(f.bx[1],f.by[1]), G0(f.bx[2],f.by[2])};
    if (l == 63) {                                   // i>=512 -> Go
        if (PH == 0) { vB.z = Go0; vB.w = Go1; }
        if (PH == 1) { vB.w = Go0; }
    }
    *(f32x4*)(a0p + 4 * (l + 65)) = vB;

    // chunk C: k = l+129
    f32x4 vC = (f32x4){H(xy0.x, xy0.y, qw.x), H(xy0.z, xy0.w, qw.y),
                       H(xy1.x, xy1.y, qw.z), H(xy1.z, xy1.w, qw.w)};
    if (l == 0) {                                    // m<0 -> G511/Go
        if (PH == 1) { vC.x = Go1; }
        if (PH == 2) { vC.x = Go0; vC.y = Go1; }
        if (PH == 3) { vC.x = G1(f.e255x, f.e255y); vC.y = Go0; vC.z = Go1; }
    }
    *(f32x4*)(a0p + 4 * (l + 129)) = vC;

    // head chunk k=0 (lane 0)
    if (l == 0) {
        if (PH == 0) {
            *(f32x4*)a0p = (f32x4){x31_0, x31_1, G0(f.o0x,f.o0y), G1(f.o0x,f.o0y)};
        } else if (PH == 1) {
            a0p[1] = x31_0;
            *(f32x2*)(a0p + 2) = (f32x2){x31_1, G0(f.o0x,f.o0y)};
        } else if (PH == 2) {
            *(f32x2*)(a0p + 2) = (f32x2){x31_0, x31_1};
        } else {
            a0p[3] = x31_0;
        }
    }
    // tail chunk k=193 (lane 1)
    else if (l == 1) {
        float* tp = a0p + 772;                       // 16B-aligned
        if (PH == 0) {
            tp[0] = ho;
        } else if (PH == 1) {
            *(f32x2*)tp = (f32x2){H(f.Tx[2],f.Ty[2],f.Tq[2]), ho};
        } else if (PH == 2) {
            *(f32x2*)tp = (f32x2){H(f.Tx[1],f.Ty[1],f.Tq[1]),
                                  H(f.Tx[2],f.Ty[2],f.Tq[2])};
            tp[2] = ho;
        } else {
            *(f32x4*)tp = (f32x4){H(f.Tx[0],f.Ty[0],f.Tq[0]),
                                  H(f.Tx[1],f.Ty[1],f.Tq[1]),
                                  H(f.Tx[2],f.Ty[2],f.Tq[2]), ho};
        }
    }
}

__global__ __launch_bounds__(256, 4) void fused9(
    const float* __restrict__ x,
    const float* __restrict__ obstacles,
    const float* __restrict__ input_mean, const float* __restrict__ input_std,
    const float* __restrict__ W1,  const float* __restrict__ b1,
    const float* __restrict__ W21, const float* __restrict__ b21,
    const float* __restrict__ W22, const float* __restrict__ b22,
    const float* __restrict__ W31, const float* __restrict__ b31,
    const float* __restrict__ W32, const float* __restrict__ b32,
    float* __restrict__ out)
{
    __shared__ float pacc[2][64][33];      // partial acc exchange (+1 pad)
    __shared__ float prm[64][16];          // per-row coefficients
    __shared__ float oxy4[4][260][2];      // shifted (ox,oy): [p][i]=obst(i-p)
    __shared__ float Q[4][260];            // shifted q:       [p][i]=q(i-p)

    const int tid  = threadIdx.x;
    const int l    = tid & 63;
    const int wv   = __builtin_amdgcn_readfirstlane(tid >> 6);
    const int role = wv & 1;
    const int half = wv >> 1;
    const int row  = blockIdx.x * 64 + l;

    // ---- obstacle staging into LDS (complete before first sync) -----------
    {
        const float* o = obstacles + (size_t)tid * 3;
        const float a = o[0], b = o[1], r = o[2] + 0.6f;   // R=0.5+rad+0.1
        const float q = fmaf(a, a, b * b) - r * r;
        #pragma unroll
        for (int p = 0; p < 4; ++p) {
            oxy4[p][tid + p][0] = a;
            oxy4[p][tid + p][1] = b;
            Q[p][tid + p] = q;
        }
        #pragma unroll
        for (int p = 1; p < 4; ++p) {
            if (tid < p) {                 // zero the [0,p) pads (values are
                oxy4[p][tid][0] = 0.f;     // only consumed by overridden slots)
                oxy4[p][tid][1] = 0.f;
                Q[p][tid] = 0.f;
            }
        }
    }

    // ======================= Phase A: MLP + coefficients (R10, proven) =====
    float xr[8];
    {
        const float4 xa = *(const float4*)(x + (size_t)row * 8);
        const float4 xb = *(const float4*)(x + (size_t)row * 8 + 4);
        xr[0]=xa.x; xr[1]=xa.y; xr[2]=xa.z; xr[3]=xa.w;
        xr[4]=xb.x; xr[5]=xb.y; xr[6]=xb.z; xr[7]=xb.w;
    }

    const float* Wh = role ? W22 : W21;
    const float* bh = role ? b22 : b21;

    float acc[32];
    #pragma unroll
    for (int k = 0; k < 32; ++k) acc[k] = half ? 0.0f : bh[k];

    const int ibeg = half * 64;
    #pragma unroll 1
    for (int i0 = ibeg; i0 < ibeg + 64; i0 += 8) {
        float hh[8];
        #pragma unroll
        for (int u = 0; u < 8; ++u) {
            float a = b1[i0 + u];
            #pragma unroll
            for (int k = 0; k < 8; ++k)
                a = fmaf(xr[k], W1[k * 128 + i0 + u], a);
            hh[u] = fmaxf(a, 0.0f);
        }
        #pragma unroll
        for (int u = 0; u < 8; ++u) {
            #pragma unroll
            for (int k = 0; k < 32; ++k)
                acc[k] = fmaf(hh[u], Wh[(i0 + u) * 32 + k], acc[k]);
        }
    }

    if (half == 0) {
        #pragma unroll
        for (int k = 0; k < 32; ++k) pacc[role][l][k] = acc[k];
    }
    __syncthreads();

    if (half == 1) {
        #pragma unroll
        for (int k = 0; k < 32; ++k) acc[k] += pacc[role][l][k];

        const float* Wo = role ? W32 : W31;
        const float* bo = role ? b32 : b31;
        float o0 = bo[0], o1 = bo[1];
        #pragma unroll
        for (int k = 0; k < 32; ++k) {
            float a = fmaxf(acc[k], 0.0f);
            o0 = fmaf(a, Wo[k * 2 + 0], o0);
            o1 = fmaf(a, Wo[k * 2 + 1], o1);
        }

        float x0v[8];
        #pragma unroll
        for (int k = 0; k < 8; ++k)
            x0v[k] = fmaf(xr[k], input_std[k], input_mean[k]);
        const float px = x0v[0], py = x0v[1], th = x0v[2], v = x0v[3];
        const float opx = x0v[4], opy = x0v[5], oth = x0v[6], ov = x0v[7];

        float st, ct, sto, cto;
        sincosf(th,  &st,  &ct);
        sincosf(oth, &sto, &cto);

        const float tvs = 2.0f * v * st;
        const float tvc = 2.0f * v * ct;
        const float tc  = 2.0f * ct;
        const float ts  = 2.0f * st;
        const float hc  = 2.0f * v * v;

        const float dxo = px - opx, dyo = py - opy;

        if (role == 0) {
            const float A0  = px * tvs - py * tvc;
            const float A1  = -(px * tc + py * ts);
            const float Go0 = dxo * tvs - dyo * tvc;
            const float Go1 = -(dxo * tc + dyo * ts);
            *(f32x4*)&prm[l][0] = (f32x4){A0, tvs, tvc, A1};
            *(f32x4*)&prm[l][4] = (f32x4){tc, ts, o0, o1};
            *(f32x2*)&prm[l][8] = (f32x2){Go0, Go1};
        } else {
            const float p0 = 4.0f / (1.0f + __expf(-o0));
            const float p1 = 4.0f / (1.0f + __expf(-o1));
            const float ps = p0 + p1;
            const float pp = p0 * p1;
            const float B0 = px * tvc + py * tvs;
            const float C  = hc + ps * B0 + pp * (px * px + py * py);
            const float u  = -(ps * tvc) - 2.0f * pp * px;
            const float w  = -(ps * tvs) - 2.0f * pp * py;
            const float ob  = dxo * dxo + dyo * dyo - 1.21f;     // Ro^2
            const float rvx = v * ct - ov * cto;
            const float rvy = v * st - ov * sto;
            const float obd = 2.0f * (dxo * rvx + dyo * rvy);
            const float cth_sum = ct * cto - st * sto;            // cos(th+oth)
            const float oLf2b = 2.0f * (v * v + ov * ov - 2.0f * v * ov * cth_sum);
            const float ho = oLf2b + ps * obd + pp * ob;
            *(f32x2*)&prm[l][10]  = (f32x2){ho, 0.0f};
            *(f32x4*)&prm[l][12]  = (f32x4){C, u, w, pp};
        }
    }
    __syncthreads();

    // ======================= Phase B: linear rows per wave ==================
    // G-chunk union feats in registers (R9 windows, correctness-proven).
    GFeats f;
    #pragma unroll
    for (int c = 0; c < 4; ++c) {
        const int j = iclamp(2 * l - 1 + c, 0, 255);
        const float* o = obstacles + (size_t)j * 3;
        f.ax[c] = o[0]; f.ay[c] = o[1];
    }
    #pragma unroll
    for (int c = 0; c < 4; ++c) {
        const int j = iclamp(2 * l + 127 + c, 0, 255);
        const float* o = obstacles + (size_t)j * 3;
        f.bx[c] = o[0]; f.by[c] = o[1];
    }
    f.o0x = obstacles[0]; f.o0y = obstacles[1];
    f.e255x = obstacles[255 * 3]; f.e255y = obstacles[255 * 3 + 1];
    #pragma unroll
    for (int c = 0; c < 3; ++c) {
        const float* o = obstacles + (size_t)(253 + c) * 3;
        const float a = o[0], b = o[1], r = o[2] + 0.6f;
        f.Tx[c] = a; f.Ty[c] = b; f.Tq[c] = fmaf(a, a, b * b) - r * r;
    }

    const int blockRow0 = blockIdx.x * 64;
    const int r0  = blockRow0 + wv * 16;   // 16 CONSECUTIVE rows per wave
    const int rl0 = wv * 16;

    #pragma unroll 1
    for (int g = 0; g < 4; ++g) {
        const int rb  = r0  + g * 4;
        const int rlb = rl0 + g * 4;
        b_row2<0>(rb + 0, rlb + 0, l, prm, oxy4, Q, f, out);
        __builtin_amdgcn_sched_barrier(0);   // one row in flight (R9 lesson)
        b_row2<1>(rb + 1, rlb + 1, l, prm, oxy4, Q, f, out);
        __builtin_amdgcn_sched_barrier(0);
        b_row2<2>(rb + 2, rlb + 2, l, prm, oxy4, Q, f, out);
        __builtin_amdgcn_sched_barrier(0);
        b_row2<3>(rb + 3, rlb + 3, l, prm, oxy4, Q, f, out);
        __builtin_amdgcn_sched_barrier(0);
    }
}

extern "C" void kernel_launch(void* const* d_in, const int* in_sizes, int n_in,
                              void* d_out, int out_size, void* d_ws, size_t ws_size,
                              hipStream_t stream) {
    const float* x          = (const float*)d_in[0];
    const float* obstacles  = (const float*)d_in[1];
    const float* input_mean = (const float*)d_in[2];
    const float* input_std  = (const float*)d_in[3];
    const float* W1  = (const float*)d_in[4];
    const float* b1  = (const float*)d_in[5];
    const float* W21 = (const float*)d_in[6];
    const float* b21 = (const float*)d_in[7];
    const float* W22 = (const float*)d_in[8];
    const float* b22 = (const float*)d_in[9];
    const float* W31 = (const float*)d_in[10];
    const float* b31 = (const float*)d_in[11];
    const float* W32 = (const float*)d_in[12];
    const float* b32 = (const float*)d_in[13];

    float* out = (float*)d_out;

    // 1024 blocks x 256 threads, 64 rows/block.
    fused9<<<dim3(NB_TOTAL / 64), dim3(256), 0, stream>>>(
        x, obstacles, input_mean, input_std,
        W1, b1, W21, b21, W22, b22, W31, b31, W32, b32, out);
}